// Round 3
// baseline (390.871 us; speedup 1.0000x reference)
//
#include <hip/hip_runtime.h>
#include <math.h>

#define D_    64
#define K_    1024
#define N_    131072
#define HW_   4096
#define ROWS  256
#define KC    128
#define NT    512
#define NCHUNK (K_ / KC)   // 8

typedef unsigned long long ull;

// 16B half-block XOR swizzle within a 128-float row: eb reads spread over all
// 8 bank-quads (2 lanes/bank = free per m136).
__device__ __forceinline__ int col_swz(int kk) {
    int h = kk >> 2;
    int hs = h ^ ((h >> 3) & 7);
    return (hs << 2) | (kk & 3);
}

__global__ __launch_bounds__(256)
void vq_init(const float* __restrict__ emb, int* __restrict__ hist,
             double* __restrict__ ssqd, float* __restrict__ e2g) {
    int k = blockIdx.x * 256 + threadIdx.x;
    if (k < K_) {
        hist[k] = 0;
        float s = 0.0f;
        const float* e = emb + (size_t)k * D_;
        #pragma unroll
        for (int d = 0; d < D_; ++d) s = fmaf(e[d], e[d], s);  // ascending d
        e2g[k] = s;
    }
    if (k == 0 && blockIdx.x == 0) *ssqd = 0.0;
}

__global__ __launch_bounds__(NT, 4)
void vq_main(const float* __restrict__ x, const float* __restrict__ emb,
             const float* __restrict__ e2g, float* __restrict__ zq_out,
             int* __restrict__ hist, double* __restrict__ ssqd) {
    __shared__ __align__(16) float et[D_ * KC];   // 32 KB, [d][swz(kk)]
    __shared__ __align__(16) int   bidxs[ROWS];   // 1 KB
    __shared__ float wsum[NT / 64];

    const int tid = threadIdx.x;
    const int bid = blockIdx.x;
    const int n0  = bid * ROWS;
    const int b   = n0 >> 12;
    const int hw0 = n0 & (HW_ - 1);
    const float* xb = x + (size_t)b * (D_ * HW_) + hw0;

    const int kg  = tid & 15;          // 16 k-groups x 8 k
    const int rg  = tid >> 4;          // 32 r-groups x 8 r
    const int r0  = rg * 8;
    const int kk0 = kg * 8;
    const int h0  = kg * 2;
    const int eoff0 = ((h0 ^ ((h0 >> 3) & 7)) << 2);
    const int h1  = h0 + 1;
    const int eoff1 = ((h1 ^ ((h1 >> 3) & 7)) << 2);

    float r2v[8];
    float bd[8]; int bk[8];
    #pragma unroll
    for (int i = 0; i < 8; ++i) { r2v[i] = 0.0f; bd[i] = 3.4e38f; bk[i] = 0; }

    for (int c = 0; c < NCHUNK; ++c) {
        const int kbase = c * KC;
        if (c) __syncthreads();        // et safe to overwrite

        // ---- stage emb chunk transposed + swizzled into LDS ----
        #pragma unroll
        for (int i = 0; i < 4; ++i) {
            int li = i * NT + tid;     // 0..2047
            int kk = li & (KC - 1);
            int d4 = (li >> 7) << 2;   // 0,4,..,60
            float4 v = *(const float4*)(emb + (size_t)(kbase + kk) * D_ + d4);
            int sc = col_swz(kk);
            et[(d4 + 0) * KC + sc] = v.x;
            et[(d4 + 1) * KC + sc] = v.y;
            et[(d4 + 2) * KC + sc] = v.z;
            et[(d4 + 3) * KC + sc] = v.w;
        }
        __syncthreads();

        // ---- 8x8 register tile: z from global (L1/L2 broadcast), e from LDS ----
        float acc[8][8];
        #pragma unroll
        for (int i = 0; i < 8; ++i)
            #pragma unroll
            for (int j = 0; j < 8; ++j) acc[i][j] = 0.0f;

        if (c == 0) {
            #pragma unroll 4
            for (int d = 0; d < D_; ++d) {
                const float4 za0 = *(const float4*)(xb + (size_t)d * HW_ + r0);
                const float4 za1 = *(const float4*)(xb + (size_t)d * HW_ + r0 + 4);
                const float4 eb0 = *(const float4*)(et + d * KC + eoff0);
                const float4 eb1 = *(const float4*)(et + d * KC + eoff1);
                const float zr[8] = {za0.x, za0.y, za0.z, za0.w, za1.x, za1.y, za1.z, za1.w};
                const float ek[8] = {eb0.x, eb0.y, eb0.z, eb0.w, eb1.x, eb1.y, eb1.z, eb1.w};
                #pragma unroll
                for (int i = 0; i < 8; ++i) r2v[i] = fmaf(zr[i], zr[i], r2v[i]);  // ascending d
                #pragma unroll
                for (int i = 0; i < 8; ++i)
                    #pragma unroll
                    for (int j = 0; j < 8; ++j)
                        acc[i][j] = fmaf(zr[i], ek[j], acc[i][j]);
            }
        } else {
            #pragma unroll 4
            for (int d = 0; d < D_; ++d) {
                const float4 za0 = *(const float4*)(xb + (size_t)d * HW_ + r0);
                const float4 za1 = *(const float4*)(xb + (size_t)d * HW_ + r0 + 4);
                const float4 eb0 = *(const float4*)(et + d * KC + eoff0);
                const float4 eb1 = *(const float4*)(et + d * KC + eoff1);
                const float zr[8] = {za0.x, za0.y, za0.z, za0.w, za1.x, za1.y, za1.z, za1.w};
                const float ek[8] = {eb0.x, eb0.y, eb0.z, eb0.w, eb1.x, eb1.y, eb1.z, eb1.w};
                #pragma unroll
                for (int i = 0; i < 8; ++i)
                    #pragma unroll
                    for (int j = 0; j < 8; ++j)
                        acc[i][j] = fmaf(zr[i], ek[j], acc[i][j]);
            }
        }

        // ---- dist + running argmin (strict <, ascending k) ----
        float e2v[8];
        *(float4*)(e2v)     = *(const float4*)(e2g + kbase + kk0);
        *(float4*)(e2v + 4) = *(const float4*)(e2g + kbase + kk0 + 4);
        #pragma unroll
        for (int i = 0; i < 8; ++i) {
            #pragma unroll
            for (int j = 0; j < 8; ++j) {
                float dist = fmaf(-2.0f, acc[i][j], r2v[i] + e2v[j]);  // == (r2+e2)-2*acc bitwise
                int k = kbase + kk0 + j;
                if (dist < bd[i]) { bd[i] = dist; bk[i] = k; }
            }
        }
    }

    // ---- cross-kg argmin: 16-lane butterfly on packed (distbits<<32 | k) ----
    #pragma unroll
    for (int i = 0; i < 8; ++i) {
        ull p = ((ull)__float_as_uint(bd[i]) << 32) | (unsigned int)bk[i];
        #pragma unroll
        for (int off = 1; off < 16; off <<= 1) {
            ull q = __shfl_xor(p, off, 64);
            if (q < p) p = q;
        }
        if (kg == 0) {
            int k = (int)(p & 0xffffffffull);
            bidxs[r0 + i] = k;
            atomicAdd(&hist[k], 1);
        }
    }
    __syncthreads();

    // ---- epilogue: z from global, gather e, scalar stores (out+1 misaligned) ----
    float ls = 0.0f;
    float* outb = zq_out + (size_t)b * (D_ * HW_) + hw0;
    #pragma unroll
    for (int i = 0; i < 8; ++i) {
        int li = i * NT + tid;         // 0..4095
        int d  = li >> 6;
        int r4 = (li & 63) << 2;
        float4 z = *(const float4*)(xb + (size_t)d * HW_ + r4);
        int4 kv = *(const int4*)(bidxs + r4);
        float e0 = emb[(size_t)kv.x * D_ + d];
        float e1 = emb[(size_t)kv.y * D_ + d];
        float e2 = emb[(size_t)kv.z * D_ + d];
        float e3 = emb[(size_t)kv.w * D_ + d];
        float t0 = e0 - z.x, t1 = e1 - z.y, t2 = e2 - z.z, t3 = e3 - z.w;
        ls = fmaf(t0, t0, ls); ls = fmaf(t1, t1, ls);
        ls = fmaf(t2, t2, ls); ls = fmaf(t3, t3, ls);
        float* op = outb + (size_t)d * HW_ + r4;
        op[0] = z.x + t0; op[1] = z.y + t1; op[2] = z.z + t2; op[3] = z.w + t3;
    }

    #pragma unroll
    for (int o = 32; o > 0; o >>= 1) ls += __shfl_down(ls, o, 64);
    if ((tid & 63) == 0) wsum[tid >> 6] = ls;
    __syncthreads();
    if (tid == 0) {
        float s = 0.0f;
        #pragma unroll
        for (int w = 0; w < NT / 64; ++w) s += wsum[w];
        atomicAdd(ssqd, (double)s);
    }
}

__global__ __launch_bounds__(1024)
void vq_final(const int* __restrict__ hist, const double* __restrict__ ssqd,
              float* __restrict__ out_loss, float* __restrict__ out_perp) {
    __shared__ float wred[16];
    int t = threadIdx.x;
    float cnt = (float)hist[t];
    float em  = cnt / (float)N_;
    float s   = em * logf(em + 1e-10f);
    #pragma unroll
    for (int o = 32; o > 0; o >>= 1) s += __shfl_down(s, o, 64);
    if ((t & 63) == 0) wred[t >> 6] = s;
    __syncthreads();
    if (t == 0) {
        float tot = 0.0f;
        for (int w = 0; w < 16; ++w) tot += wred[w];
        *out_perp = expf(-tot);
        float mse = (float)(*ssqd / (double)((size_t)N_ * D_));
        *out_loss = mse + 0.25f * mse;
    }
}

extern "C" void kernel_launch(void* const* d_in, const int* in_sizes, int n_in,
                              void* d_out, int out_size, void* d_ws, size_t ws_size,
                              hipStream_t stream) {
    const float* x   = (const float*)d_in[0];
    const float* emb = (const float*)d_in[1];
    float* out  = (float*)d_out;
    float* loss = out;
    float* zq   = out + 1;
    float* perp = out + 1 + (size_t)N_ * D_;
    int*    hist = (int*)d_ws;
    double* ssqd = (double*)((char*)d_ws + K_ * sizeof(int));
    float*  e2g  = (float*)((char*)d_ws + K_ * sizeof(int) + 16);

    vq_init<<<dim3(4), dim3(256), 0, stream>>>(emb, hist, ssqd, e2g);
    vq_main<<<dim3(N_ / ROWS), dim3(NT), 0, stream>>>(x, emb, e2g, zq, hist, ssqd);
    vq_final<<<dim3(1), dim3(1024), 0, stream>>>(hist, ssqd, loss, perp);
}

// Round 4
// 229.963 us; speedup vs baseline: 1.6997x; 1.6997x over previous
//
#include <hip/hip_runtime.h>
#include <math.h>

#define D_    64
#define K_    1024
#define N_    131072
#define HW_   4096
#define ROWS  128
#define KC    128
#define NT    256
#define NCHUNK (K_ / KC)   // 8

typedef unsigned long long ull;

// 16B half-block XOR swizzle within a 128-float row: spreads the 16 kg-lane
// b128 read addresses over all 8 bank-quads (2/quad = free per m136).
__device__ __forceinline__ int col_swz(int kk) {
    int h = kk >> 2;
    int hs = h ^ ((h >> 3) & 7);
    return (hs << 2) | (kk & 3);
}

__global__ __launch_bounds__(256)
void vq_init(const float* __restrict__ emb, int* __restrict__ hist,
             double* __restrict__ ssqd, float* __restrict__ e2g) {
    int k = blockIdx.x * 256 + threadIdx.x;
    if (k < K_) {
        hist[k] = 0;
        float s = 0.0f;
        const float* e = emb + (size_t)k * D_;
        #pragma unroll
        for (int d = 0; d < D_; ++d) s = fmaf(e[d], e[d], s);  // ascending d
        e2g[k] = s;
    }
    if (k == 0 && blockIdx.x == 0) *ssqd = 0.0;
}

__global__ __launch_bounds__(NT)
void vq_main(const float* __restrict__ x, const float* __restrict__ emb,
             const float* __restrict__ e2g, float* __restrict__ zq_out,
             int* __restrict__ hist, double* __restrict__ ssqd) {
    __shared__ __align__(16) float zt[D_ * ROWS];   // 32 KB [d][r]
    __shared__ __align__(16) float et[D_ * KC];     // 32 KB [d][swz(kk)]
    __shared__ float r2s[ROWS];
    __shared__ int   bidxs[ROWS];
    __shared__ float wsum[NT / 64];

    const int tid = threadIdx.x;
    const int bid = blockIdx.x;
    const int n0  = bid * ROWS;
    const int b   = n0 >> 12;
    const int hw0 = n0 & (HW_ - 1);
    const float* xb = x + (size_t)b * (D_ * HW_) + hw0;

    // ---- load z tile (coalesced float4) ----
    #pragma unroll
    for (int i = 0; i < 8; ++i) {
        int li = i * NT + tid;          // 0..2047
        int d  = li >> 5;
        int r4 = (li & 31) << 2;
        *(float4*)(zt + d * ROWS + r4) = *(const float4*)(xb + (size_t)d * HW_ + r4);
    }

    // ---- prefetch emb chunk 0 into registers (overlaps r2 section) ----
    float4 pf[8];
    #pragma unroll
    for (int i = 0; i < 8; ++i) {
        int li = i * NT + tid;          // 0..2047
        int kk = li & (KC - 1);
        int d4 = (li >> 7) << 2;        // 0,4,..,60
        pf[i] = *(const float4*)(emb + (size_t)kk * D_ + d4);
    }

    __syncthreads();                    // zt visible

    // ---- r2 per row (ascending-d fma chain: bitwise == rounds 1-3) ----
    if (tid < ROWS) {
        float s = 0.0f;
        for (int d = 0; d < D_; ++d) { float z = zt[d * ROWS + tid]; s = fmaf(z, z, s); }
        r2s[tid] = s;
    }

    const int kg  = tid & 15;           // 16 k-groups x 8 k
    const int rg  = tid >> 4;           // 16 r-groups x 8 r
    const int r0  = rg * 8;
    const int kk0 = kg * 8;
    const int h0  = kg * 2;
    const int eoff0 = ((h0 ^ ((h0 >> 3) & 7)) << 2);
    const int h1  = h0 + 1;
    const int eoff1 = ((h1 ^ ((h1 >> 3) & 7)) << 2);

    float r2v[8];
    float bd[8]; int bk[8];
    #pragma unroll
    for (int i = 0; i < 8; ++i) { bd[i] = 3.4e38f; bk[i] = 0; }

    for (int c = 0; c < NCHUNK; ++c) {
        const int kbase = c * KC;
        if (c) __syncthreads();         // previous chunk's readers done

        // ---- write prefetched chunk into LDS (transposed + swizzled) ----
        #pragma unroll
        for (int i = 0; i < 8; ++i) {
            int li = i * NT + tid;
            int kk = li & (KC - 1);
            int d4 = (li >> 7) << 2;
            int sc = col_swz(kk);
            et[(d4 + 0) * KC + sc] = pf[i].x;
            et[(d4 + 1) * KC + sc] = pf[i].y;
            et[(d4 + 2) * KC + sc] = pf[i].z;
            et[(d4 + 3) * KC + sc] = pf[i].w;
        }
        __syncthreads();

        if (c == 0) {
            #pragma unroll
            for (int i = 0; i < 8; ++i) r2v[i] = r2s[r0 + i];
        }
        float e2v[8];
        *(float4*)(e2v)     = *(const float4*)(e2g + kbase + kk0);
        *(float4*)(e2v + 4) = *(const float4*)(e2g + kbase + kk0 + 4);

        // ---- issue next chunk's global loads; they fly under the compute ----
        if (c + 1 < NCHUNK) {
            const float* ebase = emb + (size_t)(kbase + KC) * D_;
            #pragma unroll
            for (int i = 0; i < 8; ++i) {
                int li = i * NT + tid;
                int kk = li & (KC - 1);
                int d4 = (li >> 7) << 2;
                pf[i] = *(const float4*)(ebase + (size_t)kk * D_ + d4);
            }
        }

        // ---- 8x8 register tile dot products ----
        float acc[8][8];
        #pragma unroll
        for (int i = 0; i < 8; ++i)
            #pragma unroll
            for (int j = 0; j < 8; ++j) acc[i][j] = 0.0f;

        #pragma unroll 4
        for (int d = 0; d < D_; ++d) {
            const float4 za0 = *(const float4*)(zt + d * ROWS + r0);
            const float4 za1 = *(const float4*)(zt + d * ROWS + r0 + 4);
            const float4 eb0 = *(const float4*)(et + d * KC + eoff0);
            const float4 eb1 = *(const float4*)(et + d * KC + eoff1);
            const float zr[8] = {za0.x, za0.y, za0.z, za0.w, za1.x, za1.y, za1.z, za1.w};
            const float ek[8] = {eb0.x, eb0.y, eb0.z, eb0.w, eb1.x, eb1.y, eb1.z, eb1.w};
            #pragma unroll
            for (int i = 0; i < 8; ++i)
                #pragma unroll
                for (int j = 0; j < 8; ++j)
                    acc[i][j] = fmaf(zr[i], ek[j], acc[i][j]);
        }

        // ---- dist + running argmin (strict <, ascending k) ----
        #pragma unroll
        for (int i = 0; i < 8; ++i) {
            #pragma unroll
            for (int j = 0; j < 8; ++j) {
                float dist = fmaf(-2.0f, acc[i][j], r2v[i] + e2v[j]);  // == (r2+e2)-2*acc bitwise
                int k = kbase + kk0 + j;
                if (dist < bd[i]) { bd[i] = dist; bk[i] = k; }
            }
        }
    }

    // ---- cross-kg argmin: 16-lane butterfly on packed (distbits<<32 | k) ----
    #pragma unroll
    for (int i = 0; i < 8; ++i) {
        ull p = ((ull)__float_as_uint(bd[i]) << 32) | (unsigned int)bk[i];
        #pragma unroll
        for (int off = 1; off < 16; off <<= 1) {
            ull q = __shfl_xor(p, off, 64);
            if (q < p) p = q;
        }
        if (kg == 0) {
            int k = (int)(p & 0xffffffffull);
            bidxs[r0 + i] = k;
            atomicAdd(&hist[k], 1);
        }
    }
    __syncthreads();

    // ---- epilogue: z from LDS, gather e (L2-hot), scalar coalesced stores ----
    float ls = 0.0f;
    float* outb = zq_out + (size_t)b * (D_ * HW_) + hw0;
    #pragma unroll 4
    for (int it = 0; it < 32; ++it) {
        int li = it * NT + tid;         // 0..8191
        int r  = li & (ROWS - 1);
        int d  = li >> 7;
        int k  = bidxs[r];
        float e = emb[(size_t)k * D_ + d];
        float z = zt[d * ROWS + r];
        float t = e - z;
        ls = fmaf(t, t, ls);
        outb[(size_t)d * HW_ + r] = z + t;
    }

    #pragma unroll
    for (int o = 32; o > 0; o >>= 1) ls += __shfl_down(ls, o, 64);
    if ((tid & 63) == 0) wsum[tid >> 6] = ls;
    __syncthreads();
    if (tid == 0) {
        float s = 0.0f;
        #pragma unroll
        for (int w = 0; w < NT / 64; ++w) s += wsum[w];
        atomicAdd(ssqd, (double)s);
    }
}

__global__ __launch_bounds__(1024)
void vq_final(const int* __restrict__ hist, const double* __restrict__ ssqd,
              float* __restrict__ out_loss, float* __restrict__ out_perp) {
    __shared__ float wred[16];
    int t = threadIdx.x;
    float cnt = (float)hist[t];
    float em  = cnt / (float)N_;
    float s   = em * logf(em + 1e-10f);
    #pragma unroll
    for (int o = 32; o > 0; o >>= 1) s += __shfl_down(s, o, 64);
    if ((t & 63) == 0) wred[t >> 6] = s;
    __syncthreads();
    if (t == 0) {
        float tot = 0.0f;
        for (int w = 0; w < 16; ++w) tot += wred[w];
        *out_perp = expf(-tot);
        float mse = (float)(*ssqd / (double)((size_t)N_ * D_));
        *out_loss = mse + 0.25f * mse;
    }
}

extern "C" void kernel_launch(void* const* d_in, const int* in_sizes, int n_in,
                              void* d_out, int out_size, void* d_ws, size_t ws_size,
                              hipStream_t stream) {
    const float* x   = (const float*)d_in[0];
    const float* emb = (const float*)d_in[1];
    float* out  = (float*)d_out;
    float* loss = out;
    float* zq   = out + 1;
    float* perp = out + 1 + (size_t)N_ * D_;
    int*    hist = (int*)d_ws;
    double* ssqd = (double*)((char*)d_ws + K_ * sizeof(int));
    float*  e2g  = (float*)((char*)d_ws + K_ * sizeof(int) + 16);

    vq_init<<<dim3(4), dim3(256), 0, stream>>>(emb, hist, ssqd, e2g);
    vq_main<<<dim3(N_ / ROWS), dim3(NT), 0, stream>>>(x, emb, e2g, zq, hist, ssqd);
    vq_final<<<dim3(1), dim3(1024), 0, stream>>>(hist, ssqd, loss, perp);
}